// Round 8
// baseline (404.925 us; speedup 1.0000x reference)
//
#include <hip/hip_runtime.h>
#include <hip/hip_bf16.h>
#include <math.h>

#define DIM 256
#define B_SEG 512
#define LN_EPS 1e-5f

typedef __attribute__((ext_vector_type(8))) short bf16x8;
typedef __attribute__((ext_vector_type(4))) float f32x4;

__device__ __forceinline__ float gelu_exact(float v) {
    return 0.5f * v * (1.0f + erff(v * 0.70710678118654752f));
}

__device__ __forceinline__ unsigned int pack2bf(float a, float b) {
    unsigned int ua = (unsigned int)__bfloat16_as_ushort(__float2bfloat16(a));
    unsigned int ub = (unsigned int)__bfloat16_as_ushort(__float2bfloat16(b));
    return ua | (ub << 16);
}

__device__ __forceinline__ float bf2f(short s) {
    return __uint_as_float(((unsigned int)(unsigned short)s) << 16);
}

__device__ __forceinline__ void async16(const void* g, void* l) {
    __builtin_amdgcn_global_load_lds(
        (const __attribute__((address_space(1))) void*)(g),
        (__attribute__((address_space(3))) void*)(l), 16, 0, 0);
}

// ---- Kernel 0: Wg top half -> Wt2, k-chunk-major: Wt2[(k>>3)*2048 + c*8 + (k&7)]
__global__ __launch_bounds__(256) void k_wprep(const float* __restrict__ Wg,
                                               __hip_bfloat16* __restrict__ Wt2) {
    int k = blockIdx.x;   // 0..255 (input k row)
    int c = threadIdx.x;  // 0..255 (output col)
    Wt2[((size_t)(k >> 3) << 11) + (c << 3) + (k & 7)] = __float2bfloat16(Wg[(size_t)k * DIM + c]);
}

// ---- Kernel A: pure streaming convert x (fp32) -> xbf (pre-swizzled bf16) ----
// m13 copy shape: 16 independent float4 loads per wave-pass, fence, 16 stores.
__global__ __launch_bounds__(256) void k_convert(const float* __restrict__ x,
                                                 __hip_bfloat16* __restrict__ xbf,
                                                 int n) {
    const int t    = threadIdx.x;
    const int lane = t & 63;
    const int rg   = t >> 6;
    const int step = gridDim.x * 64;
    for (int base = blockIdx.x * 64; base < n; base += step) {
        const int r0 = base + rg * 16;
        float4 v[16];
        #pragma unroll
        for (int j = 0; j < 16; ++j) {
            int r = r0 + j;
            v[j] = (r < n) ? *(const float4*)(x + (size_t)r * DIM + lane * 4)
                           : make_float4(0.f, 0.f, 0.f, 0.f);
        }
        __builtin_amdgcn_sched_barrier(0);   // loads stay hoisted: all 16 in flight
        #pragma unroll
        for (int j = 0; j < 16; ++j) {
            int r = r0 + j;
            if (r < n) {
                uint2 pk;
                pk.x = pack2bf(v[j].x, v[j].y);
                pk.y = pack2bf(v[j].z, v[j].w);
                *(uint2*)((char*)xbf + (size_t)r * 512 + ((lane * 8) ^ ((r & 7) << 4))) = pk;
            }
        }
    }
}

// ---- Kernel 1: segment sum + counts from xbf (bf16, L3-hot), phase-split -----
// Block = 64 rows; wave rg owns rows [R0, R0+16); half-wave parity-interleaved.
// Lane: 8 dims (d8..d8+7) of 8 rows (stride 2). All loads up front, fence, scan.
__global__ __launch_bounds__(256) void k_segsum(const __hip_bfloat16* __restrict__ xbf,
                                                const int* __restrict__ batch,
                                                float* __restrict__ sums,  // [B,D]
                                                float* __restrict__ cnt,   // [B]
                                                int n) {
    const int i0 = blockIdx.x * 64;
    if (i0 >= n) return;
    const int t    = threadIdx.x;
    const int lane = t & 63;
    const int rg   = t >> 6;
    const int half = lane >> 5;
    const int li   = lane & 31;
    const int d8   = li * 8;
    const int R0   = i0 + rg * 16;

    int    bt[8];
    bf16x8 w[8];
    #pragma unroll
    for (int j = 0; j < 8; ++j) {
        int r = R0 + half + 2 * j;
        bt[j] = (r < n) ? batch[r] : -1;
    }
    #pragma unroll
    for (int j = 0; j < 8; ++j) {
        int r = R0 + half + 2 * j;
        if (r < n) {
            w[j] = *(const bf16x8*)((const char*)xbf + (size_t)r * 512 +
                                    ((d8 * 2) ^ ((r & 7) << 4)));
        } else {
            w[j] = (bf16x8){0, 0, 0, 0, 0, 0, 0, 0};
        }
    }
    __builtin_amdgcn_sched_barrier(0);   // keep all 16 loads in flight

    float acc[8] = {0.f, 0.f, 0.f, 0.f, 0.f, 0.f, 0.f, 0.f};
    int cur = -1, run = 0;
    #pragma unroll
    for (int j = 0; j < 8; ++j) {
        if (bt[j] != cur) {
            if (cur >= 0) {
                #pragma unroll
                for (int e = 0; e < 8; ++e)
                    atomicAdd(&sums[(size_t)cur * DIM + d8 + e], acc[e]);
                if (li == 0) atomicAdd(&cnt[cur], (float)run);
            }
            #pragma unroll
            for (int e = 0; e < 8; ++e) acc[e] = 0.f;
            run = 0; cur = bt[j];
        }
        #pragma unroll
        for (int e = 0; e < 8; ++e) acc[e] += bf2f(w[j][e]);
        run++;
    }
    if (cur >= 0) {
        #pragma unroll
        for (int e = 0; e < 8; ++e)
            atomicAdd(&sums[(size_t)cur * DIM + d8 + e], acc[e]);
        if (li == 0) atomicAdd(&cnt[cur], (float)run);
    }
}

// ---------------- Kernel 2: per-segment VN pipeline (4-way split dots) --------
__global__ __launch_bounds__(256) void k_vn(const float* __restrict__ sums,
                                            const float* __restrict__ cnt,
                                            const float* __restrict__ vn_embed,
                                            const float* __restrict__ W1, const float* __restrict__ b1,
                                            const float* __restrict__ g1, const float* __restrict__ be1,
                                            const float* __restrict__ W2, const float* __restrict__ b2,
                                            const float* __restrict__ g2, const float* __restrict__ be2,
                                            const float* __restrict__ Wg, const float* __restrict__ bg,
                                            float* __restrict__ vn_state_out, // [B,D]
                                            float* __restrict__ nu,           // ws [B,D]
                                            float* __restrict__ gpart) {      // ws [B,D]
    __shared__ float sIn[DIM];
    __shared__ float sRed[DIM];
    __shared__ float sRed2[DIM];
    const int b = blockIdx.x;
    const int d = threadIdx.x;

    float c = cnt[b];
    float denom = fmaxf(c, 1.0f);
    sIn[d] = sums[(size_t)b * DIM + d] / denom;
    __syncthreads();

    float h0 = 0.f, h1 = 0.f, h2a = 0.f, h3 = 0.f;
    for (int k = 0; k < DIM; k += 4) {
        h0  = fmaf(sIn[k + 0], W1[(size_t)(k + 0) * DIM + d], h0);
        h1  = fmaf(sIn[k + 1], W1[(size_t)(k + 1) * DIM + d], h1);
        h2a = fmaf(sIn[k + 2], W1[(size_t)(k + 2) * DIM + d], h2a);
        h3  = fmaf(sIn[k + 3], W1[(size_t)(k + 3) * DIM + d], h3);
    }
    float h = gelu_exact(b1[d] + ((h0 + h1) + (h2a + h3)));

    sRed[d] = h; sRed2[d] = h * h;
    __syncthreads();
    for (int s = 128; s > 0; s >>= 1) {
        if (d < s) { sRed[d] += sRed[d + s]; sRed2[d] += sRed2[d + s]; }
        __syncthreads();
    }
    float mu = sRed[0] * (1.0f / DIM);
    float var = fmaxf(sRed2[0] * (1.0f / DIM) - mu * mu, 0.0f);
    float rs = rsqrtf(var + LN_EPS);
    float vnst = vn_embed[d] + ((h - mu) * rs * g1[d] + be1[d]);
    vn_state_out[(size_t)b * DIM + d] = vnst;
    __syncthreads();
    sIn[d] = vnst;
    __syncthreads();

    float g0 = 0.f, g1a = 0.f, g2a = 0.f, g3 = 0.f;
    for (int k = 0; k < DIM; k += 4) {
        g0  = fmaf(sIn[k + 0], W2[(size_t)(k + 0) * DIM + d], g0);
        g1a = fmaf(sIn[k + 1], W2[(size_t)(k + 1) * DIM + d], g1a);
        g2a = fmaf(sIn[k + 2], W2[(size_t)(k + 2) * DIM + d], g2a);
        g3  = fmaf(sIn[k + 3], W2[(size_t)(k + 3) * DIM + d], g3);
    }
    float h2 = gelu_exact(b2[d] + ((g0 + g1a) + (g2a + g3)));

    sRed[d] = h2; sRed2[d] = h2 * h2;
    __syncthreads();
    for (int s = 128; s > 0; s >>= 1) {
        if (d < s) { sRed[d] += sRed[d + s]; sRed2[d] += sRed2[d + s]; }
        __syncthreads();
    }
    float mu2 = sRed[0] * (1.0f / DIM);
    float var2 = fmaxf(sRed2[0] * (1.0f / DIM) - mu2 * mu2, 0.0f);
    float rs2 = rsqrtf(var2 + LN_EPS);
    float nud = (h2 - mu2) * rs2 * g2[d] + be2[d];
    nu[(size_t)b * DIM + d] = nud;
    __syncthreads();
    sIn[d] = nud;
    __syncthreads();

    float p0 = 0.f, p1 = 0.f, p2 = 0.f, p3 = 0.f;
    for (int k = 0; k < DIM; k += 4) {
        p0 = fmaf(sIn[k + 0], Wg[(size_t)(DIM + k + 0) * DIM + d], p0);
        p1 = fmaf(sIn[k + 1], Wg[(size_t)(DIM + k + 1) * DIM + d], p1);
        p2 = fmaf(sIn[k + 2], Wg[(size_t)(DIM + k + 2) * DIM + d], p2);
        p3 = fmaf(sIn[k + 3], Wg[(size_t)(DIM + k + 3) * DIM + d], p3);
    }
    gpart[(size_t)b * DIM + d] = bg[d] + ((p0 + p1) + (p2 + p3));
}

// ---- Kernel 3a (bf16 path): gate GEMM, A via global_load_lds from xbf --------
__global__ __launch_bounds__(256, 4) void k_gate_bf(const __hip_bfloat16* __restrict__ xbf,
                                                    const int* __restrict__ batch,
                                                    const __hip_bfloat16* __restrict__ Wt2,
                                                    const float* __restrict__ nu,    // [B,D]
                                                    const float* __restrict__ gpart, // [B,D]
                                                    float* __restrict__ xout,
                                                    int n) {
    __shared__ __align__(16) char sA[64 * 512];   // 32 KB, pre-swizzled rows

    const int tid  = threadIdx.x;
    const int wave = tid >> 6;
    const int lane = tid & 63;
    const int r15  = lane & 15;
    const int kq   = lane >> 4;
    const size_t i0 = (size_t)blockIdx.x * 64;

    // stage: 8 x 16B async copies per thread; LDS dest wave-uniform base (m104)
    const char* gsrc = (const char*)xbf + i0 * 512;
    #pragma unroll
    for (int j = 0; j < 8; ++j)
        async16(gsrc + j * 4096 + tid * 16, sA + j * 4096 + wave * 1024);
    __syncthreads();   // compiler inserts vmcnt(0) drain here

    f32x4 acc[4][4];
    #pragma unroll
    for (int m = 0; m < 4; ++m)
        #pragma unroll
        for (int nn = 0; nn < 4; ++nn)
            acc[m][nn] = (f32x4){0.f, 0.f, 0.f, 0.f};

    #pragma unroll
    for (int ks = 0; ks < 8; ++ks) {
        bf16x8 a[4], b[4];
        #pragma unroll
        for (int nn = 0; nn < 4; ++nn) {
            int c = wave * 64 + nn * 16 + r15;
            b[nn] = *(const bf16x8*)(Wt2 + ((size_t)(ks * 4 + kq) << 11) + (c << 3));
        }
        #pragma unroll
        for (int m = 0; m < 4; ++m) {
            int r = m * 16 + r15;
            a[m] = *(const bf16x8*)(sA + r * 512 + ((ks * 64 + kq * 16) ^ ((r & 7) << 4)));
        }
        #pragma unroll
        for (int m = 0; m < 4; ++m)
            #pragma unroll
            for (int nn = 0; nn < 4; ++nn)
                acc[m][nn] = __builtin_amdgcn_mfma_f32_16x16x32_bf16(a[m], b[nn], acc[m][nn], 0, 0, 0);
    }

    // epilogue: + gpart[seg], sigmoid, residual (LDS bf16) + g*nu
    #pragma unroll
    for (int m = 0; m < 4; ++m) {
        #pragma unroll
        for (int q = 0; q < 4; ++q) {
            int rr = m * 16 + kq * 4 + q;
            long node = (long)(i0 + rr);
            if (node >= n) continue;
            int bb = batch[node];
            #pragma unroll
            for (int nn = 0; nn < 4; ++nn) {
                int col = wave * 64 + nn * 16 + r15;
                float pre = acc[m][nn][q] + gpart[bb * DIM + col];
                float e = __expf(-pre);
                float gte = __builtin_amdgcn_rcpf(1.0f + e);
                float xres = __bfloat162float(
                    *(const __hip_bfloat16*)(sA + rr * 512 + ((2 * col) ^ ((rr & 7) << 4))));
                xout[(size_t)node * DIM + col] = xres + gte * nu[bb * DIM + col];
            }
        }
    }
}

// ---- Fallback kernels (used only if ws too small for xbf) -------------------
__global__ __launch_bounds__(256) void k_segsum_fp(const float* __restrict__ x,
                                                   const int* __restrict__ batch,
                                                   float* __restrict__ sums,
                                                   float* __restrict__ cnt,
                                                   int n) {
    const int i0 = blockIdx.x * 64;
    if (i0 >= n) return;
    const int t    = threadIdx.x;
    const int lane = t & 63;
    const int d4   = lane * 4;
    const int rg   = t >> 6;
    float4 acc = make_float4(0.f, 0.f, 0.f, 0.f);
    int cur = -1, run = 0;
    for (int j = 0; j < 16; ++j) {
        int i = i0 + rg + 4 * j;
        if (i >= n) break;
        int b = batch[i];
        if (b != cur) {
            if (cur >= 0) {
                atomicAdd(&sums[(size_t)cur * DIM + d4 + 0], acc.x);
                atomicAdd(&sums[(size_t)cur * DIM + d4 + 1], acc.y);
                atomicAdd(&sums[(size_t)cur * DIM + d4 + 2], acc.z);
                atomicAdd(&sums[(size_t)cur * DIM + d4 + 3], acc.w);
                if (d4 == 0) atomicAdd(&cnt[cur], (float)run);
            }
            acc = make_float4(0.f, 0.f, 0.f, 0.f);
            run = 0; cur = b;
        }
        float4 v = *(const float4*)(x + (size_t)i * DIM + d4);
        acc.x += v.x; acc.y += v.y; acc.z += v.z; acc.w += v.w;
        run++;
    }
    if (cur >= 0) {
        atomicAdd(&sums[(size_t)cur * DIM + d4 + 0], acc.x);
        atomicAdd(&sums[(size_t)cur * DIM + d4 + 1], acc.y);
        atomicAdd(&sums[(size_t)cur * DIM + d4 + 2], acc.z);
        atomicAdd(&sums[(size_t)cur * DIM + d4 + 3], acc.w);
        if (d4 == 0) atomicAdd(&cnt[cur], (float)run);
    }
}

__global__ __launch_bounds__(256) void k_gate_fp(const float* __restrict__ x,
                                                 const int* __restrict__ batch,
                                                 const __hip_bfloat16* __restrict__ Wt2,
                                                 const float* __restrict__ nu,
                                                 const float* __restrict__ gpart,
                                                 float* __restrict__ xout,
                                                 int n) {
    __shared__ __align__(16) char sA[32 * 512];
    const int tid  = threadIdx.x;
    const int wave = tid >> 6;
    const int lane = tid & 63;
    const int r15  = lane & 15;
    const int kq   = lane >> 4;
    const int i0   = blockIdx.x * 32;

    float4 av0[4], av1[4];
    #pragma unroll
    for (int j = 0; j < 4; ++j) {
        int v = j * 256 + tid;
        int r = v >> 5;
        int k8 = v & 31;
        int node = i0 + r;
        if (node < n) {
            const float* p = x + (size_t)node * DIM + k8 * 8;
            av0[j] = *(const float4*)p;
            av1[j] = *(const float4*)(p + 4);
        } else {
            av0[j] = make_float4(0.f, 0.f, 0.f, 0.f);
            av1[j] = av0[j];
        }
    }
    #pragma unroll
    for (int j = 0; j < 4; ++j) {
        int v = j * 256 + tid;
        int r = v >> 5;
        int k8 = v & 31;
        uint4 pk;
        pk.x = pack2bf(av0[j].x, av0[j].y);
        pk.y = pack2bf(av0[j].z, av0[j].w);
        pk.z = pack2bf(av1[j].x, av1[j].y);
        pk.w = pack2bf(av1[j].z, av1[j].w);
        *(uint4*)(sA + r * 512 + ((k8 * 16) ^ ((r & 7) << 4))) = pk;
    }
    __syncthreads();

    f32x4 acc[2][4];
    #pragma unroll
    for (int m = 0; m < 2; ++m)
        #pragma unroll
        for (int nn = 0; nn < 4; ++nn)
            acc[m][nn] = (f32x4){0.f, 0.f, 0.f, 0.f};

    #pragma unroll
    for (int ks = 0; ks < 8; ++ks) {
        bf16x8 a[2], b[4];
        #pragma unroll
        for (int nn = 0; nn < 4; ++nn) {
            int c = wave * 64 + nn * 16 + r15;
            b[nn] = *(const bf16x8*)(Wt2 + ((size_t)(ks * 4 + kq) << 11) + (c << 3));
        }
        #pragma unroll
        for (int m = 0; m < 2; ++m) {
            int r = m * 16 + r15;
            a[m] = *(const bf16x8*)(sA + r * 512 + ((ks * 64 + kq * 16) ^ ((r & 7) << 4)));
        }
        #pragma unroll
        for (int m = 0; m < 2; ++m)
            #pragma unroll
            for (int nn = 0; nn < 4; ++nn)
                acc[m][nn] = __builtin_amdgcn_mfma_f32_16x16x32_bf16(a[m], b[nn], acc[m][nn], 0, 0, 0);
    }

    #pragma unroll
    for (int m = 0; m < 2; ++m) {
        #pragma unroll
        for (int q = 0; q < 4; ++q) {
            int rr = m * 16 + kq * 4 + q;
            int node = i0 + rr;
            if (node >= n) continue;
            int bb = batch[node];
            #pragma unroll
            for (int nn = 0; nn < 4; ++nn) {
                int col = wave * 64 + nn * 16 + r15;
                float pre = acc[m][nn][q] + gpart[bb * DIM + col];
                float e = __expf(-pre);
                float gte = __builtin_amdgcn_rcpf(1.0f + e);
                float xres = __bfloat162float(
                    *(const __hip_bfloat16*)(sA + rr * 512 + ((2 * col) ^ ((rr & 7) << 4))));
                xout[(size_t)node * DIM + col] = xres + gte * nu[bb * DIM + col];
            }
        }
    }
}

extern "C" void kernel_launch(void* const* d_in, const int* in_sizes, int n_in,
                              void* d_out, int out_size, void* d_ws, size_t ws_size,
                              hipStream_t stream) {
    const float* x        = (const float*)d_in[0];
    const int*   batch    = (const int*)d_in[1];
    const float* vn_embed = (const float*)d_in[2];
    const float* W1  = (const float*)d_in[3];
    const float* b1  = (const float*)d_in[4];
    const float* g1  = (const float*)d_in[5];
    const float* be1 = (const float*)d_in[6];
    const float* W2  = (const float*)d_in[7];
    const float* b2  = (const float*)d_in[8];
    const float* g2  = (const float*)d_in[9];
    const float* be2 = (const float*)d_in[10];
    const float* Wg  = (const float*)d_in[11];
    const float* bg  = (const float*)d_in[12];

    const int n = in_sizes[0] / DIM;

    float* out = (float*)d_out;
    float* xout = out;                              // [N,D]
    float* vn_state_out = out + (size_t)n * DIM;    // [B,D]

    float* ws    = (float*)d_ws;
    float* sums  = ws;                                   // B*D
    float* cnt   = sums + (size_t)B_SEG * DIM;           // B
    float* nu    = cnt + B_SEG;                          // B*D
    float* gpart = nu + (size_t)B_SEG * DIM;             // B*D
    __hip_bfloat16* Wt2 = (__hip_bfloat16*)(gpart + (size_t)B_SEG * DIM); // 64K bf16
    __hip_bfloat16* xbf = Wt2 + (size_t)DIM * DIM;       // [ntile64*64][256] bf16

    const size_t base_bytes = ((size_t)B_SEG * DIM * 3 + B_SEG) * 4 + (size_t)DIM * DIM * 2;
    const int nt64 = (n + 63) / 64;
    const size_t need = base_bytes + (size_t)nt64 * 64 * 512;
    const bool use_bf = (ws_size >= need);

    hipMemsetAsync(d_ws, 0, ((size_t)B_SEG * DIM + B_SEG) * sizeof(float), stream);

    k_wprep<<<DIM, DIM, 0, stream>>>(Wg, Wt2);

    if (use_bf) {
        int cblk = (nt64 < 2048) ? nt64 : 2048;
        k_convert<<<cblk, 256, 0, stream>>>(x, xbf, n);
        k_segsum<<<nt64, 256, 0, stream>>>(xbf, batch, sums, cnt, n);
    } else {
        k_segsum_fp<<<nt64, 256, 0, stream>>>(x, batch, sums, cnt, n);
    }

    k_vn<<<B_SEG, 256, 0, stream>>>(sums, cnt, vn_embed,
                                    W1, b1, g1, be1,
                                    W2, b2, g2, be2,
                                    Wg, bg,
                                    vn_state_out, nu, gpart);

    if (use_bf) {
        k_gate_bf<<<nt64, 256, 0, stream>>>(xbf, batch, Wt2, nu, gpart, xout, n);
    } else {
        int nblk3 = (n + 31) / 32;
        k_gate_fp<<<nblk3, 256, 0, stream>>>(x, batch, Wt2, nu, gpart, xout, n);
    }
}

// Round 9
// 197.223 us; speedup vs baseline: 2.0531x; 2.0531x over previous
//
#include <hip/hip_runtime.h>
#include <hip/hip_bf16.h>
#include <math.h>

#define DIM 256
#define B_SEG 512
#define LN_EPS 1e-5f

typedef __attribute__((ext_vector_type(8))) short bf16x8;
typedef __attribute__((ext_vector_type(4))) float f32x4;

__device__ __forceinline__ float gelu_exact(float v) {
    return 0.5f * v * (1.0f + erff(v * 0.70710678118654752f));
}

__device__ __forceinline__ unsigned int pack2bf(float a, float b) {
    unsigned int ua = (unsigned int)__bfloat16_as_ushort(__float2bfloat16(a));
    unsigned int ub = (unsigned int)__bfloat16_as_ushort(__float2bfloat16(b));
    return ua | (ub << 16);
}

__device__ __forceinline__ void async16(const void* g, void* l) {
    __builtin_amdgcn_global_load_lds(
        (const __attribute__((address_space(1))) void*)(g),
        (__attribute__((address_space(3))) void*)(l), 16, 0, 0);
}

// ---- Kernel 0: Wg top half -> Wt2, k-chunk-major: Wt2[(k>>3)*2048 + c*8 + (k&7)]
__global__ __launch_bounds__(256) void k_wprep(const float* __restrict__ Wg,
                                               __hip_bfloat16* __restrict__ Wt2) {
    int k = blockIdx.x;   // 0..255 (input k row)
    int c = threadIdx.x;  // 0..255 (output col)
    Wt2[((size_t)(k >> 3) << 11) + (c << 3) + (k & 7)] = __float2bfloat16(Wg[(size_t)k * DIM + c]);
}

// ---- Kernel B: segment bounds via binary search (batch is sorted) ------------
__global__ __launch_bounds__(256) void k_bounds(const int* __restrict__ batch,
                                                int* __restrict__ seg_start, int n) {
    int s = blockIdx.x * 256 + threadIdx.x;   // 0..512
    if (s > B_SEG) return;
    int lo = 0, hi = n;                        // first i with batch[i] >= s
    while (lo < hi) {
        int mid = (lo + hi) >> 1;
        if (batch[mid] < s) lo = mid + 1; else hi = mid;
    }
    seg_start[s] = lo;
}

// ---- Kernel 1: segment sum, one block per (segment, half). NO ATOMICS. -------
// 256 thr = 4 waves; wave w owns rows r0+4j+w; lane owns dims [4*lane,4*lane+4).
// Also emits pre-swizzled bf16 copy of x (consumed by k_gate_bf).
__global__ __launch_bounds__(256) void k_segsum2(const float* __restrict__ x,
                                                 const int* __restrict__ seg_start,
                                                 float* __restrict__ partial, // [2][B][D]
                                                 __hip_bfloat16* __restrict__ xbf,
                                                 int emit) {
    const int seg  = blockIdx.x >> 1;
    const int half = blockIdx.x & 1;
    const int s0 = seg_start[seg], s1 = seg_start[seg + 1];
    const int hl = (s1 - s0 + 1) >> 1;
    const int rs = s0 + half * hl;
    const int re = half ? s1 : (s0 + hl);

    const int wave = threadIdx.x >> 6;
    const int lane = threadIdx.x & 63;
    const int dby  = lane * 8;                // byte offset of this lane's 4 dims (bf16)

    float4 acc = make_float4(0.f, 0.f, 0.f, 0.f);

    for (int r0 = rs; r0 < re; r0 += 16) {
        float4 v[4];
        #pragma unroll
        for (int jj = 0; jj < 4; ++jj) {
            int r = r0 + 4 * jj + wave;
            v[jj] = (r < re) ? *(const float4*)(x + (size_t)r * DIM + lane * 4)
                             : make_float4(0.f, 0.f, 0.f, 0.f);
        }
        __builtin_amdgcn_sched_barrier(0);    // keep the 4 row-loads grouped
        #pragma unroll
        for (int jj = 0; jj < 4; ++jj) {
            int r = r0 + 4 * jj + wave;
            if (r < re) {
                if (emit) {
                    uint2 pk;
                    pk.x = pack2bf(v[jj].x, v[jj].y);
                    pk.y = pack2bf(v[jj].z, v[jj].w);
                    *(uint2*)((char*)xbf + (size_t)r * 512 + (dby ^ ((r & 7) << 4))) = pk;
                }
                acc.x += v[jj].x; acc.y += v[jj].y; acc.z += v[jj].z; acc.w += v[jj].w;
            }
        }
    }

    // cross-wave reduce (4 partials per dim), then ONE plain store per dim
    __shared__ float4 red[4][64];
    red[wave][lane] = acc;
    __syncthreads();
    if (wave == 0) {
        float4 a0 = red[0][lane], a1 = red[1][lane], a2 = red[2][lane], a3 = red[3][lane];
        float4 t;
        t.x = (a0.x + a1.x) + (a2.x + a3.x);
        t.y = (a0.y + a1.y) + (a2.y + a3.y);
        t.z = (a0.z + a1.z) + (a2.z + a3.z);
        t.w = (a0.w + a1.w) + (a2.w + a3.w);
        *(float4*)(partial + ((size_t)half * B_SEG + seg) * DIM + lane * 4) = t;
    }
}

// ---------------- Kernel 2: per-segment VN pipeline (4-way split dots) --------
__global__ __launch_bounds__(256) void k_vn(const float* __restrict__ partial, // [2][B][D]
                                            const int* __restrict__ seg_start,
                                            const float* __restrict__ vn_embed,
                                            const float* __restrict__ W1, const float* __restrict__ b1,
                                            const float* __restrict__ g1, const float* __restrict__ be1,
                                            const float* __restrict__ W2, const float* __restrict__ b2,
                                            const float* __restrict__ g2, const float* __restrict__ be2,
                                            const float* __restrict__ Wg, const float* __restrict__ bg,
                                            float* __restrict__ vn_state_out, // [B,D]
                                            float* __restrict__ nu,           // ws [B,D]
                                            float* __restrict__ gpart) {      // ws [B,D]
    __shared__ float sIn[DIM];
    __shared__ float sRed[DIM];
    __shared__ float sRed2[DIM];
    const int b = blockIdx.x;
    const int d = threadIdx.x;

    float cntf = (float)(seg_start[b + 1] - seg_start[b]);
    float denom = fmaxf(cntf, 1.0f);
    sIn[d] = (partial[(size_t)b * DIM + d] +
              partial[(size_t)(B_SEG + b) * DIM + d]) / denom;
    __syncthreads();

    float h0 = 0.f, h1 = 0.f, h2a = 0.f, h3 = 0.f;
    for (int k = 0; k < DIM; k += 4) {
        h0  = fmaf(sIn[k + 0], W1[(size_t)(k + 0) * DIM + d], h0);
        h1  = fmaf(sIn[k + 1], W1[(size_t)(k + 1) * DIM + d], h1);
        h2a = fmaf(sIn[k + 2], W1[(size_t)(k + 2) * DIM + d], h2a);
        h3  = fmaf(sIn[k + 3], W1[(size_t)(k + 3) * DIM + d], h3);
    }
    float h = gelu_exact(b1[d] + ((h0 + h1) + (h2a + h3)));

    sRed[d] = h; sRed2[d] = h * h;
    __syncthreads();
    for (int s = 128; s > 0; s >>= 1) {
        if (d < s) { sRed[d] += sRed[d + s]; sRed2[d] += sRed2[d + s]; }
        __syncthreads();
    }
    float mu = sRed[0] * (1.0f / DIM);
    float var = fmaxf(sRed2[0] * (1.0f / DIM) - mu * mu, 0.0f);
    float rs = rsqrtf(var + LN_EPS);
    float vnst = vn_embed[d] + ((h - mu) * rs * g1[d] + be1[d]);
    vn_state_out[(size_t)b * DIM + d] = vnst;
    __syncthreads();
    sIn[d] = vnst;
    __syncthreads();

    float g0 = 0.f, g1a = 0.f, g2a = 0.f, g3 = 0.f;
    for (int k = 0; k < DIM; k += 4) {
        g0  = fmaf(sIn[k + 0], W2[(size_t)(k + 0) * DIM + d], g0);
        g1a = fmaf(sIn[k + 1], W2[(size_t)(k + 1) * DIM + d], g1a);
        g2a = fmaf(sIn[k + 2], W2[(size_t)(k + 2) * DIM + d], g2a);
        g3  = fmaf(sIn[k + 3], W2[(size_t)(k + 3) * DIM + d], g3);
    }
    float h2 = gelu_exact(b2[d] + ((g0 + g1a) + (g2a + g3)));

    sRed[d] = h2; sRed2[d] = h2 * h2;
    __syncthreads();
    for (int s = 128; s > 0; s >>= 1) {
        if (d < s) { sRed[d] += sRed[d + s]; sRed2[d] += sRed2[d + s]; }
        __syncthreads();
    }
    float mu2 = sRed[0] * (1.0f / DIM);
    float var2 = fmaxf(sRed2[0] * (1.0f / DIM) - mu2 * mu2, 0.0f);
    float rs2 = rsqrtf(var2 + LN_EPS);
    float nud = (h2 - mu2) * rs2 * g2[d] + be2[d];
    nu[(size_t)b * DIM + d] = nud;
    __syncthreads();
    sIn[d] = nud;
    __syncthreads();

    float p0 = 0.f, p1 = 0.f, p2 = 0.f, p3 = 0.f;
    for (int k = 0; k < DIM; k += 4) {
        p0 = fmaf(sIn[k + 0], Wg[(size_t)(DIM + k + 0) * DIM + d], p0);
        p1 = fmaf(sIn[k + 1], Wg[(size_t)(DIM + k + 1) * DIM + d], p1);
        p2 = fmaf(sIn[k + 2], Wg[(size_t)(DIM + k + 2) * DIM + d], p2);
        p3 = fmaf(sIn[k + 3], Wg[(size_t)(DIM + k + 3) * DIM + d], p3);
    }
    gpart[(size_t)b * DIM + d] = bg[d] + ((p0 + p1) + (p2 + p3));
}

// ---- Kernel 3a (bf16 path): gate GEMM, A via global_load_lds from xbf --------
__global__ __launch_bounds__(256, 4) void k_gate_bf(const __hip_bfloat16* __restrict__ xbf,
                                                    const int* __restrict__ batch,
                                                    const __hip_bfloat16* __restrict__ Wt2,
                                                    const float* __restrict__ nu,    // [B,D]
                                                    const float* __restrict__ gpart, // [B,D]
                                                    float* __restrict__ xout,
                                                    int n) {
    __shared__ __align__(16) char sA[64 * 512];   // 32 KB, pre-swizzled rows

    const int tid  = threadIdx.x;
    const int wave = tid >> 6;
    const int lane = tid & 63;
    const int r15  = lane & 15;
    const int kq   = lane >> 4;
    const size_t i0 = (size_t)blockIdx.x * 64;

    // stage: 8 x 16B async copies per thread; LDS dest wave-uniform base (m104)
    const char* gsrc = (const char*)xbf + i0 * 512;
    #pragma unroll
    for (int j = 0; j < 8; ++j)
        async16(gsrc + j * 4096 + tid * 16, sA + j * 4096 + wave * 1024);
    __syncthreads();   // compiler inserts vmcnt(0) drain here

    f32x4 acc[4][4];
    #pragma unroll
    for (int m = 0; m < 4; ++m)
        #pragma unroll
        for (int nn = 0; nn < 4; ++nn)
            acc[m][nn] = (f32x4){0.f, 0.f, 0.f, 0.f};

    #pragma unroll
    for (int ks = 0; ks < 8; ++ks) {
        bf16x8 a[4], b[4];
        #pragma unroll
        for (int nn = 0; nn < 4; ++nn) {
            int c = wave * 64 + nn * 16 + r15;
            b[nn] = *(const bf16x8*)(Wt2 + ((size_t)(ks * 4 + kq) << 11) + (c << 3));
        }
        #pragma unroll
        for (int m = 0; m < 4; ++m) {
            int r = m * 16 + r15;
            a[m] = *(const bf16x8*)(sA + r * 512 + ((ks * 64 + kq * 16) ^ ((r & 7) << 4)));
        }
        #pragma unroll
        for (int m = 0; m < 4; ++m)
            #pragma unroll
            for (int nn = 0; nn < 4; ++nn)
                acc[m][nn] = __builtin_amdgcn_mfma_f32_16x16x32_bf16(a[m], b[nn], acc[m][nn], 0, 0, 0);
    }

    // epilogue: + gpart[seg], sigmoid, residual (LDS bf16) + g*nu
    #pragma unroll
    for (int m = 0; m < 4; ++m) {
        #pragma unroll
        for (int q = 0; q < 4; ++q) {
            int rr = m * 16 + kq * 4 + q;
            long node = (long)(i0 + rr);
            if (node >= n) continue;
            int bb = batch[node];
            #pragma unroll
            for (int nn = 0; nn < 4; ++nn) {
                int col = wave * 64 + nn * 16 + r15;
                float pre = acc[m][nn][q] + gpart[bb * DIM + col];
                float e = __expf(-pre);
                float gte = __builtin_amdgcn_rcpf(1.0f + e);
                float xres = __bfloat162float(
                    *(const __hip_bfloat16*)(sA + rr * 512 + ((2 * col) ^ ((rr & 7) << 4))));
                xout[(size_t)node * DIM + col] = xres + gte * nu[bb * DIM + col];
            }
        }
    }
}

// ---- Fallback kernels (used only if ws too small for xbf) -------------------
__global__ __launch_bounds__(256) void k_segsum_fp(const float* __restrict__ x,
                                                   const int* __restrict__ batch,
                                                   float* __restrict__ sums,
                                                   int n) {
    const int i0 = blockIdx.x * 64;
    if (i0 >= n) return;
    const int t    = threadIdx.x;
    const int lane = t & 63;
    const int d4   = lane * 4;
    const int rg   = t >> 6;
    float4 acc = make_float4(0.f, 0.f, 0.f, 0.f);
    int cur = -1;
    for (int j = 0; j < 16; ++j) {
        int i = i0 + rg + 4 * j;
        if (i >= n) break;
        int b = batch[i];
        if (b != cur) {
            if (cur >= 0) {
                atomicAdd(&sums[(size_t)cur * DIM + d4 + 0], acc.x);
                atomicAdd(&sums[(size_t)cur * DIM + d4 + 1], acc.y);
                atomicAdd(&sums[(size_t)cur * DIM + d4 + 2], acc.z);
                atomicAdd(&sums[(size_t)cur * DIM + d4 + 3], acc.w);
            }
            acc = make_float4(0.f, 0.f, 0.f, 0.f);
            cur = b;
        }
        float4 v = *(const float4*)(x + (size_t)i * DIM + d4);
        acc.x += v.x; acc.y += v.y; acc.z += v.z; acc.w += v.w;
    }
    if (cur >= 0) {
        atomicAdd(&sums[(size_t)cur * DIM + d4 + 0], acc.x);
        atomicAdd(&sums[(size_t)cur * DIM + d4 + 1], acc.y);
        atomicAdd(&sums[(size_t)cur * DIM + d4 + 2], acc.z);
        atomicAdd(&sums[(size_t)cur * DIM + d4 + 3], acc.w);
    }
}

__global__ __launch_bounds__(256) void k_gate_fp(const float* __restrict__ x,
                                                 const int* __restrict__ batch,
                                                 const __hip_bfloat16* __restrict__ Wt2,
                                                 const float* __restrict__ nu,
                                                 const float* __restrict__ gpart,
                                                 float* __restrict__ xout,
                                                 int n) {
    __shared__ __align__(16) char sA[32 * 512];
    const int tid  = threadIdx.x;
    const int wave = tid >> 6;
    const int lane = tid & 63;
    const int r15  = lane & 15;
    const int kq   = lane >> 4;
    const int i0   = blockIdx.x * 32;

    float4 av0[4], av1[4];
    #pragma unroll
    for (int j = 0; j < 4; ++j) {
        int v = j * 256 + tid;
        int r = v >> 5;
        int k8 = v & 31;
        int node = i0 + r;
        if (node < n) {
            const float* p = x + (size_t)node * DIM + k8 * 8;
            av0[j] = *(const float4*)p;
            av1[j] = *(const float4*)(p + 4);
        } else {
            av0[j] = make_float4(0.f, 0.f, 0.f, 0.f);
            av1[j] = av0[j];
        }
    }
    #pragma unroll
    for (int j = 0; j < 4; ++j) {
        int v = j * 256 + tid;
        int r = v >> 5;
        int k8 = v & 31;
        uint4 pk;
        pk.x = pack2bf(av0[j].x, av0[j].y);
        pk.y = pack2bf(av0[j].z, av0[j].w);
        pk.z = pack2bf(av1[j].x, av1[j].y);
        pk.w = pack2bf(av1[j].z, av1[j].w);
        *(uint4*)(sA + r * 512 + ((k8 * 16) ^ ((r & 7) << 4))) = pk;
    }
    __syncthreads();

    f32x4 acc[2][4];
    #pragma unroll
    for (int m = 0; m < 2; ++m)
        #pragma unroll
        for (int nn = 0; nn < 4; ++nn)
            acc[m][nn] = (f32x4){0.f, 0.f, 0.f, 0.f};

    #pragma unroll
    for (int ks = 0; ks < 8; ++ks) {
        bf16x8 a[2], b[4];
        #pragma unroll
        for (int nn = 0; nn < 4; ++nn) {
            int c = wave * 64 + nn * 16 + r15;
            b[nn] = *(const bf16x8*)(Wt2 + ((size_t)(ks * 4 + kq) << 11) + (c << 3));
        }
        #pragma unroll
        for (int m = 0; m < 2; ++m) {
            int r = m * 16 + r15;
            a[m] = *(const bf16x8*)(sA + r * 512 + ((ks * 64 + kq * 16) ^ ((r & 7) << 4)));
        }
        #pragma unroll
        for (int m = 0; m < 2; ++m)
            #pragma unroll
            for (int nn = 0; nn < 4; ++nn)
                acc[m][nn] = __builtin_amdgcn_mfma_f32_16x16x32_bf16(a[m], b[nn], acc[m][nn], 0, 0, 0);
    }

    #pragma unroll
    for (int m = 0; m < 2; ++m) {
        #pragma unroll
        for (int q = 0; q < 4; ++q) {
            int rr = m * 16 + kq * 4 + q;
            int node = i0 + rr;
            if (node >= n) continue;
            int bb = batch[node];
            #pragma unroll
            for (int nn = 0; nn < 4; ++nn) {
                int col = wave * 64 + nn * 16 + r15;
                float pre = acc[m][nn][q] + gpart[bb * DIM + col];
                float e = __expf(-pre);
                float gte = __builtin_amdgcn_rcpf(1.0f + e);
                float xres = __bfloat162float(
                    *(const __hip_bfloat16*)(sA + rr * 512 + ((2 * col) ^ ((rr & 7) << 4))));
                xout[(size_t)node * DIM + col] = xres + gte * nu[bb * DIM + col];
            }
        }
    }
}

extern "C" void kernel_launch(void* const* d_in, const int* in_sizes, int n_in,
                              void* d_out, int out_size, void* d_ws, size_t ws_size,
                              hipStream_t stream) {
    const float* x        = (const float*)d_in[0];
    const int*   batch    = (const int*)d_in[1];
    const float* vn_embed = (const float*)d_in[2];
    const float* W1  = (const float*)d_in[3];
    const float* b1  = (const float*)d_in[4];
    const float* g1  = (const float*)d_in[5];
    const float* be1 = (const float*)d_in[6];
    const float* W2  = (const float*)d_in[7];
    const float* b2  = (const float*)d_in[8];
    const float* g2  = (const float*)d_in[9];
    const float* be2 = (const float*)d_in[10];
    const float* Wg  = (const float*)d_in[11];
    const float* bg  = (const float*)d_in[12];

    const int n = in_sizes[0] / DIM;

    float* out = (float*)d_out;
    float* xout = out;                              // [N,D]
    float* vn_state_out = out + (size_t)n * DIM;    // [B,D]

    // ws layout (all offsets multiple of 1 KB):
    char* wsb = (char*)d_ws;
    int*   seg_start = (int*)wsb;                                  // 513 ints (4 KB pad)
    float* partial   = (float*)(wsb + 4096);                       // [2][B][D] = 1 MB
    float* nu        = partial + (size_t)2 * B_SEG * DIM;          // 512 KB
    float* gpart     = nu + (size_t)B_SEG * DIM;                   // 512 KB
    __hip_bfloat16* Wt2 = (__hip_bfloat16*)(gpart + (size_t)B_SEG * DIM); // 128 KB
    __hip_bfloat16* xbf = Wt2 + (size_t)DIM * DIM;                 // [nt64*64][256] bf16

    const int nt64 = (n + 63) / 64;
    const size_t base_bytes = 4096 + (size_t)2 * B_SEG * DIM * 4
                            + (size_t)B_SEG * DIM * 4 * 2 + (size_t)DIM * DIM * 2;
    const size_t need = base_bytes + (size_t)nt64 * 64 * 512;
    const bool use_bf = (ws_size >= need);

    k_wprep<<<DIM, DIM, 0, stream>>>(Wg, Wt2);
    k_bounds<<<3, 256, 0, stream>>>(batch, seg_start, n);

    if (use_bf) {
        k_segsum2<<<2 * B_SEG, 256, 0, stream>>>(x, seg_start, partial, xbf, 1);
    } else {
        hipMemsetAsync(partial, 0, (size_t)2 * B_SEG * DIM * sizeof(float), stream);
        k_segsum_fp<<<nt64, 256, 0, stream>>>(x, batch, partial, n);
    }

    k_vn<<<B_SEG, 256, 0, stream>>>(partial, seg_start, vn_embed,
                                    W1, b1, g1, be1,
                                    W2, b2, g2, be2,
                                    Wg, bg,
                                    vn_state_out, nu, gpart);

    if (use_bf) {
        k_gate_bf<<<nt64, 256, 0, stream>>>(xbf, batch, Wt2, nu, gpart, xout, n);
    } else {
        int nblk3 = (n + 31) / 32;
        k_gate_fp<<<nblk3, 256, 0, stream>>>(x, batch, Wt2, nu, gpart, xout, n);
    }
}